// Round 3
// baseline (386.304 us; speedup 1.0000x reference)
//
#include <hip/hip_runtime.h>
#include <stdint.h>
#include <stddef.h>

#define NNODES 50000
#define NEDGES 500000
#define DIM 256
#define NHEAD 8
#define HDIM 32
#define MPAD 50048   /* 391 * 128 */
#define NEGS 0.2f
#define SCAN_BLOCKS 196  /* ceil(50000/256) */

typedef __attribute__((ext_vector_type(8))) short bf16x8;
typedef __attribute__((ext_vector_type(4))) float f32x4;
typedef __attribute__((ext_vector_type(4))) unsigned short u16x4;

__device__ __forceinline__ unsigned short f2bf(float f) {
    uint32_t u = __builtin_bit_cast(uint32_t, f);
    uint32_t r = (u + 0x7FFFu + ((u >> 16) & 1u)) >> 16;
    return (unsigned short)r;
}

__device__ __forceinline__ float bf2f(unsigned short u) {
    return __builtin_bit_cast(float, (uint32_t)u << 16);
}

__device__ __forceinline__ float leaky(float x) {
    return x > 0.0f ? x : NEGS * x;
}

__device__ __forceinline__ void gld_lds16(const unsigned short* g, unsigned short* l) {
    __builtin_amdgcn_global_load_lds(
        (const __attribute__((address_space(1))) void*)g,
        (__attribute__((address_space(3))) void*)l,
        16, 0, 0);
}

// ---------------- CSR build ----------------

__global__ __launch_bounds__(256) void count_kernel(const int* __restrict__ dst,
                                                    int* __restrict__ deg) {
    int i = blockIdx.x * 256 + threadIdx.x;
    if (i < NEDGES) atomicAdd(&deg[dst[i]], 1);
}

__global__ __launch_bounds__(256) void scanA_kernel(const int* __restrict__ deg,
                                                    int* __restrict__ bsum) {
    __shared__ int ws[4];
    int t = threadIdx.x;
    int idx = blockIdx.x * 256 + t;
    int v = (idx < NNODES) ? deg[idx] : 0;
    int x = v;
    #pragma unroll
    for (int off = 1; off < 64; off <<= 1) x += __shfl_xor(x, off, 64);
    if ((t & 63) == 0) ws[t >> 6] = x;
    __syncthreads();
    if (t == 0) bsum[blockIdx.x] = ws[0] + ws[1] + ws[2] + ws[3];
}

__global__ __launch_bounds__(256) void scanB_kernel(const int* __restrict__ bsum,
                                                    int* __restrict__ boff,
                                                    int* __restrict__ rowptr) {
    __shared__ int s[256];
    int t = threadIdx.x;
    int v = (t < SCAN_BLOCKS) ? bsum[t] : 0;
    s[t] = v;
    __syncthreads();
    #pragma unroll
    for (int off = 1; off < 256; off <<= 1) {
        int y = (t >= off) ? s[t - off] : 0;
        __syncthreads();
        s[t] += y;
        __syncthreads();
    }
    if (t < SCAN_BLOCKS) boff[t] = s[t] - v;  // exclusive
    if (t == 0) rowptr[NNODES] = NEDGES;
}

__global__ __launch_bounds__(256) void scanC_kernel(const int* __restrict__ deg,
                                                    const int* __restrict__ boff,
                                                    int* __restrict__ rowptr,
                                                    int* __restrict__ cursor) {
    __shared__ int ws[4];
    int t = threadIdx.x;
    int lane = t & 63, wv = t >> 6;
    int idx = blockIdx.x * 256 + t;
    int v = (idx < NNODES) ? deg[idx] : 0;
    int x = v;
    #pragma unroll
    for (int off = 1; off < 64; off <<= 1) {
        int y = __shfl_up(x, off, 64);
        if (lane >= off) x += y;
    }
    if (lane == 63) ws[wv] = x;
    __syncthreads();
    int wadd = 0;
    #pragma unroll
    for (int k = 0; k < 4; ++k) if (k < wv) wadd += ws[k];
    int excl = x - v + wadd + boff[blockIdx.x];
    if (idx < NNODES) { rowptr[idx] = excl; cursor[idx] = excl; }
}

__global__ __launch_bounds__(256) void fill_kernel(const int* __restrict__ src,
                                                   const int* __restrict__ dst,
                                                   int* __restrict__ cursor,
                                                   int* __restrict__ csr) {
    int i = blockIdx.x * 256 + threadIdx.x;
    if (i < NEDGES) {
        int pos = atomicAdd(&cursor[dst[i]], 1);
        csr[pos] = src[i];
    }
}

// ---------------- fp32 -> bf16 convert ----------------

__global__ __launch_bounds__(256) void cvt_kernel(const float* __restrict__ x,
                                                  unsigned short* __restrict__ y) {
    int i = (blockIdx.x * 256 + threadIdx.x) * 4;
    const float4 v = *(const float4*)(x + i);
    u16x4 o;
    o.x = f2bf(v.x); o.y = f2bf(v.y); o.z = f2bf(v.z); o.w = f2bf(v.w);
    *(u16x4*)(y + i) = o;
}

// ---------------- W [K][N] fp32 -> WT [N][K] bf16, 3 weights in one dispatch ----------------

__global__ __launch_bounds__(256) void transpose_cvt3(const float* __restrict__ W0,
                                                      const float* __restrict__ W1,
                                                      const float* __restrict__ W2,
                                                      unsigned short* __restrict__ WT) {
    __shared__ float tile[32][33];
    const float* W = (blockIdx.z == 0) ? W0 : (blockIdx.z == 1) ? W1 : W2;
    unsigned short* T = WT + (size_t)blockIdx.z * DIM * DIM;
    int bx = blockIdx.x;  // n tile
    int by = blockIdx.y;  // k tile
    int tx = threadIdx.x & 31, ty = threadIdx.x >> 5;  // 32 x 8
    #pragma unroll
    for (int j = 0; j < 4; ++j)
        tile[ty + j * 8][tx] = W[(by * 32 + ty + j * 8) * DIM + bx * 32 + tx];
    __syncthreads();
    #pragma unroll
    for (int j = 0; j < 4; ++j)
        T[(bx * 32 + ty + j * 8) * DIM + by * 32 + tx] = f2bf(tile[tx][ty + j * 8]);
}

// ---------------- GEMM: Cb[M][256](bf16) = A[M][256](bf16) @ W (+bias) ----------------

__global__ __launch_bounds__(256) void gemm_kernel(const unsigned short* __restrict__ A,
                                                   const unsigned short* __restrict__ BT,
                                                   unsigned short* __restrict__ Cb,
                                                   const float* __restrict__ bias) {
    __shared__ __align__(16) unsigned short As[128 * 32];
    __shared__ __align__(16) unsigned short Bs[128 * 32];
    int tid = threadIdx.x;
    int wave = tid >> 6, lane = tid & 63;
    int row0 = blockIdx.x * 128;
    int col0 = blockIdx.y * 128;
    int wm = (wave >> 1) * 64;
    int wn = (wave & 1) * 64;

    f32x4 acc[4][4] = {};

    int fr = lane & 15;
    int kg = (lane >> 4) * 8;

    for (int k0 = 0; k0 < DIM; k0 += 32) {
        #pragma unroll
        for (int r = 0; r < 2; ++r) {
            int row = r * 64 + (tid >> 2);
            int chunk = tid & 3;
            gld_lds16(A + (size_t)(row0 + row) * DIM + k0 + chunk * 8,
                      As + row * 32 + chunk * 8);
            gld_lds16(BT + (size_t)(col0 + row) * DIM + k0 + chunk * 8,
                      Bs + row * 32 + chunk * 8);
        }
        __syncthreads();

        bf16x8 a_frag[4], b_frag[4];
        #pragma unroll
        for (int i = 0; i < 4; ++i) {
            a_frag[i] = *(const bf16x8*)(As + (wm + i * 16 + fr) * 32 + kg);
            b_frag[i] = *(const bf16x8*)(Bs + (wn + i * 16 + fr) * 32 + kg);
        }
        #pragma unroll
        for (int i = 0; i < 4; ++i)
            #pragma unroll
            for (int j = 0; j < 4; ++j)
                acc[i][j] = __builtin_amdgcn_mfma_f32_16x16x32_bf16(
                    a_frag[i], b_frag[j], acc[i][j], 0, 0, 0);
        __syncthreads();
    }

    int rg = (lane >> 4) * 4;
    #pragma unroll
    for (int i = 0; i < 4; ++i) {
        #pragma unroll
        for (int j = 0; j < 4; ++j) {
            int n = col0 + wn + j * 16 + fr;
            float bv = bias ? bias[n] : 0.0f;
            #pragma unroll
            for (int r = 0; r < 4; ++r) {
                int m = row0 + wm + i * 16 + rg + r;
                Cb[(size_t)m * DIM + n] = f2bf(acc[i][j][r] + bv);
            }
        }
    }
}

// ---------------- el/er from bf16 h: one wave per node ----------------

__global__ __launch_bounds__(256) void eler_kernel(const unsigned short* __restrict__ Hb,
                                                   const float* __restrict__ al,
                                                   const float* __restrict__ ar,
                                                   float* __restrict__ el,
                                                   float* __restrict__ er) {
    int wave = threadIdx.x >> 6;
    int lane = threadIdx.x & 63;
    int v = blockIdx.x * 4 + wave;
    if (v >= NNODES) return;
    int c0 = lane * 4;
    ushort4 h = *(const ushort4*)(Hb + (size_t)v * DIM + c0);
    float4 a = *(const float4*)(al + c0);
    float4 r = *(const float4*)(ar + c0);
    float h0 = bf2f(h.x), h1 = bf2f(h.y), h2 = bf2f(h.z), h3 = bf2f(h.w);
    float x = h0 * a.x + h1 * a.y + h2 * a.z + h3 * a.w;
    float y = h0 * r.x + h1 * r.y + h2 * r.z + h3 * r.w;
    #pragma unroll
    for (int off = 1; off < 8; off <<= 1) {
        x += __shfl_xor(x, off, 64);
        y += __shfl_xor(y, off, 64);
    }
    if ((lane & 7) == 0) {
        int head = lane >> 3;
        el[v * NHEAD + head] = x;
        er[v * NHEAD + head] = y;
    }
}

// ---------------- edge softmax + aggregation: TWO waves per dst node ----------------
// wave half=0 covers dims [0,128), half=1 covers [128,256); each lane 2 dims.
// Doubles in-flight gathers per node; unroll-4 gives 4 independent load chains.

__global__ __launch_bounds__(256) void agg_kernel(const unsigned short* __restrict__ Hb,
                                                  const float* __restrict__ el,
                                                  const float* __restrict__ er,
                                                  const int* __restrict__ rowptr,
                                                  const int* __restrict__ csr,
                                                  const float* __restrict__ bias,
                                                  float* __restrict__ outf,
                                                  unsigned short* __restrict__ outb) {
    int tid = threadIdx.x;
    int v = blockIdx.x * 2 + (tid >> 7);
    if (v >= NNODES) return;
    int half = (tid >> 6) & 1;
    int lane = tid & 63;
    int c0 = half * 128 + lane * 2;
    int head = c0 >> 5;

    float er_v = er[v * NHEAD + head];
    float el_v = el[v * NHEAD + head];
    int beg = rowptr[v], end = rowptr[v + 1];

    // self loop
    float w = __expf(leaky(el_v + er_v));
    float z = w;
    float acc0, acc1;
    {
        ushort2 h = *(const ushort2*)(Hb + (size_t)v * DIM + c0);
        acc0 = w * bf2f(h.x); acc1 = w * bf2f(h.y);
    }

    #pragma unroll 4
    for (int i = beg; i < end; ++i) {
        int u = csr[i];
        float e = leaky(el[u * NHEAD + head] + er_v);
        float wi = __expf(e);
        z += wi;
        ushort2 h = *(const ushort2*)(Hb + (size_t)u * DIM + c0);
        acc0 += wi * bf2f(h.x);
        acc1 += wi * bf2f(h.y);
    }

    float inv = 1.0f / z;
    float2 b = *(const float2*)(bias + c0);
    float o0 = leaky(acc0 * inv + b.x);
    float o1 = leaky(acc1 * inv + b.y);
    if (outf) {
        float2 o = { o0, o1 };
        *(float2*)(outf + (size_t)v * DIM + c0) = o;
    } else {
        ushort2 o;
        o.x = f2bf(o0); o.y = f2bf(o1);
        *(ushort2*)(outb + (size_t)v * DIM + c0) = o;
    }
}

// ---------------- launch ----------------

static inline size_t align256(size_t x) { return (x + 255) & ~(size_t)255; }

extern "C" void kernel_launch(void* const* d_in, const int* in_sizes, int n_in,
                              void* d_out, int out_size, void* d_ws, size_t ws_size,
                              hipStream_t stream) {
    const float* feats  = (const float*)d_in[0];
    const int*   src    = (const int*)d_in[1];
    const int*   dst    = (const int*)d_in[2];
    const float* proj_W = (const float*)d_in[3];
    const float* proj_b = (const float*)d_in[4];
    const float* W1     = (const float*)d_in[5];
    const float* al1    = (const float*)d_in[6];
    const float* ar1    = (const float*)d_in[7];
    const float* b1     = (const float*)d_in[8];
    const float* W2     = (const float*)d_in[9];
    const float* al2    = (const float*)d_in[10];
    const float* ar2    = (const float*)d_in[11];
    const float* b2     = (const float*)d_in[12];
    float* out = (float*)d_out;

    uint8_t* w = (uint8_t*)d_ws;
    unsigned short* Abf = (unsigned short*)w; w += align256((size_t)MPAD * DIM * 2);
    unsigned short* Bbf = (unsigned short*)w; w += align256((size_t)MPAD * DIM * 2);
    unsigned short* Hb  = (unsigned short*)w; w += align256((size_t)MPAD * DIM * 2);
    unsigned short* WT  = (unsigned short*)w; w += align256((size_t)3 * DIM * DIM * 2);
    float* el = (float*)w;            w += align256((size_t)NNODES * NHEAD * 4);
    float* er = (float*)w;            w += align256((size_t)NNODES * NHEAD * 4);
    int* deg    = (int*)w;            w += align256((size_t)NNODES * 4);
    int* rowptr = (int*)w;            w += align256((size_t)(NNODES + 1) * 4);
    int* cursor = (int*)w;            w += align256((size_t)NNODES * 4);
    int* csr    = (int*)w;            w += align256((size_t)NEDGES * 4);
    int* bsum   = (int*)w;            w += align256((size_t)SCAN_BLOCKS * 4);
    int* boff   = (int*)w;            w += align256((size_t)SCAN_BLOCKS * 4);

    unsigned short* WT0 = WT;
    unsigned short* WT1 = WT + (size_t)DIM * DIM;
    unsigned short* WT2 = WT + (size_t)2 * DIM * DIM;

    const int edge_blocks = (NEDGES + 255) / 256;
    const dim3 gemm_grid(MPAD / 128, DIM / 128);
    const int eler_blocks = (NNODES + 3) / 4;   // one wave per node
    const int agg_blocks = (NNODES + 1) / 2;    // two waves per node

    // CSR build
    hipMemsetAsync(deg, 0, (size_t)NNODES * 4, stream);
    count_kernel<<<edge_blocks, 256, 0, stream>>>(dst, deg);
    scanA_kernel<<<SCAN_BLOCKS, 256, 0, stream>>>(deg, bsum);
    scanB_kernel<<<1, 256, 0, stream>>>(bsum, boff, rowptr);
    scanC_kernel<<<SCAN_BLOCKS, 256, 0, stream>>>(deg, boff, rowptr, cursor);
    fill_kernel<<<edge_blocks, 256, 0, stream>>>(src, dst, cursor, csr);

    // weights (all three) + feats to bf16
    transpose_cvt3<<<dim3(8, 8, 3), 256, 0, stream>>>(proj_W, W1, W2, WT);
    cvt_kernel<<<NNODES * DIM / 1024, 256, 0, stream>>>(feats, Abf);

    // projection: Bbf = bf16(feats @ proj_W + proj_b)
    gemm_kernel<<<gemm_grid, 256, 0, stream>>>(Abf, WT0, Bbf, proj_b);

    // layer 1: Hb = Bbf @ W1 ; agg -> Abf (bf16, input of layer-2 gemm)
    gemm_kernel<<<gemm_grid, 256, 0, stream>>>(Bbf, WT1, Hb, nullptr);
    eler_kernel<<<eler_blocks, 256, 0, stream>>>(Hb, al1, ar1, el, er);
    agg_kernel<<<agg_blocks, 256, 0, stream>>>(Hb, el, er, rowptr, csr, b1,
                                               nullptr, Abf);

    // layer 2: Hb = Abf @ W2 ; agg -> out (fp32)
    gemm_kernel<<<gemm_grid, 256, 0, stream>>>(Abf, WT2, Hb, nullptr);
    eler_kernel<<<eler_blocks, 256, 0, stream>>>(Hb, al2, ar2, el, er);
    agg_kernel<<<agg_blocks, 256, 0, stream>>>(Hb, el, er, rowptr, csr, b2,
                                               out, nullptr);
}

// Round 4
// 357.228 us; speedup vs baseline: 1.0814x; 1.0814x over previous
//
#include <hip/hip_runtime.h>
#include <stdint.h>
#include <stddef.h>

#define NNODES 50000
#define NEDGES 500000
#define DIM 256
#define NHEAD 8
#define HDIM 32
#define MPAD 50048   /* 391 * 128 */
#define NEGS 0.2f
#define SCAN_BLOCKS 196  /* ceil(50000/256) */

typedef __attribute__((ext_vector_type(8))) short bf16x8;
typedef __attribute__((ext_vector_type(4))) float f32x4;
typedef __attribute__((ext_vector_type(4))) unsigned short u16x4;

__device__ __forceinline__ unsigned short f2bf(float f) {
    uint32_t u = __builtin_bit_cast(uint32_t, f);
    uint32_t r = (u + 0x7FFFu + ((u >> 16) & 1u)) >> 16;
    return (unsigned short)r;
}

__device__ __forceinline__ float bf2f(unsigned short u) {
    return __builtin_bit_cast(float, (uint32_t)u << 16);
}

__device__ __forceinline__ float bf2f_s(short u) {
    return __builtin_bit_cast(float, (uint32_t)(unsigned short)u << 16);
}

__device__ __forceinline__ float leaky(float x) {
    return x > 0.0f ? x : NEGS * x;
}

__device__ __forceinline__ void gld_lds16(const unsigned short* g, unsigned short* l) {
    __builtin_amdgcn_global_load_lds(
        (const __attribute__((address_space(1))) void*)g,
        (__attribute__((address_space(3))) void*)l,
        16, 0, 0);
}

// ---------------- CSR build ----------------

__global__ __launch_bounds__(256) void count_kernel(const int* __restrict__ dst,
                                                    int* __restrict__ deg) {
    int i = blockIdx.x * 256 + threadIdx.x;
    if (i < NEDGES) atomicAdd(&deg[dst[i]], 1);
}

__global__ __launch_bounds__(256) void scanA_kernel(const int* __restrict__ deg,
                                                    int* __restrict__ bsum) {
    __shared__ int ws[4];
    int t = threadIdx.x;
    int idx = blockIdx.x * 256 + t;
    int v = (idx < NNODES) ? deg[idx] : 0;
    int x = v;
    #pragma unroll
    for (int off = 1; off < 64; off <<= 1) x += __shfl_xor(x, off, 64);
    if ((t & 63) == 0) ws[t >> 6] = x;
    __syncthreads();
    if (t == 0) bsum[blockIdx.x] = ws[0] + ws[1] + ws[2] + ws[3];
}

__global__ __launch_bounds__(256) void scanB_kernel(const int* __restrict__ bsum,
                                                    int* __restrict__ boff,
                                                    int* __restrict__ rowptr) {
    __shared__ int s[256];
    int t = threadIdx.x;
    int v = (t < SCAN_BLOCKS) ? bsum[t] : 0;
    s[t] = v;
    __syncthreads();
    #pragma unroll
    for (int off = 1; off < 256; off <<= 1) {
        int y = (t >= off) ? s[t - off] : 0;
        __syncthreads();
        s[t] += y;
        __syncthreads();
    }
    if (t < SCAN_BLOCKS) boff[t] = s[t] - v;  // exclusive
    if (t == 0) rowptr[NNODES] = NEDGES;
}

__global__ __launch_bounds__(256) void scanC_kernel(const int* __restrict__ deg,
                                                    const int* __restrict__ boff,
                                                    int* __restrict__ rowptr,
                                                    int* __restrict__ cursor) {
    __shared__ int ws[4];
    int t = threadIdx.x;
    int lane = t & 63, wv = t >> 6;
    int idx = blockIdx.x * 256 + t;
    int v = (idx < NNODES) ? deg[idx] : 0;
    int x = v;
    #pragma unroll
    for (int off = 1; off < 64; off <<= 1) {
        int y = __shfl_up(x, off, 64);
        if (lane >= off) x += y;
    }
    if (lane == 63) ws[wv] = x;
    __syncthreads();
    int wadd = 0;
    #pragma unroll
    for (int k = 0; k < 4; ++k) if (k < wv) wadd += ws[k];
    int excl = x - v + wadd + boff[blockIdx.x];
    if (idx < NNODES) { rowptr[idx] = excl; cursor[idx] = excl; }
}

__global__ __launch_bounds__(256) void fill_kernel(const int* __restrict__ src,
                                                   const int* __restrict__ dst,
                                                   int* __restrict__ cursor,
                                                   int* __restrict__ csr) {
    int i = blockIdx.x * 256 + threadIdx.x;
    if (i < NEDGES) {
        int pos = atomicAdd(&cursor[dst[i]], 1);
        csr[pos] = src[i];
    }
}

// ---------------- fp32 -> bf16 convert ----------------

__global__ __launch_bounds__(256) void cvt_kernel(const float* __restrict__ x,
                                                  unsigned short* __restrict__ y) {
    int i = (blockIdx.x * 256 + threadIdx.x) * 4;
    const float4 v = *(const float4*)(x + i);
    u16x4 o;
    o.x = f2bf(v.x); o.y = f2bf(v.y); o.z = f2bf(v.z); o.w = f2bf(v.w);
    *(u16x4*)(y + i) = o;
}

// ---------------- W [K][N] fp32 -> WT [N][K] bf16, 3 weights in one dispatch ----------------

__global__ __launch_bounds__(256) void transpose_cvt3(const float* __restrict__ W0,
                                                      const float* __restrict__ W1,
                                                      const float* __restrict__ W2,
                                                      unsigned short* __restrict__ WT) {
    __shared__ float tile[32][33];
    const float* W = (blockIdx.z == 0) ? W0 : (blockIdx.z == 1) ? W1 : W2;
    unsigned short* T = WT + (size_t)blockIdx.z * DIM * DIM;
    int bx = blockIdx.x;  // n tile
    int by = blockIdx.y;  // k tile
    int tx = threadIdx.x & 31, ty = threadIdx.x >> 5;  // 32 x 8
    #pragma unroll
    for (int j = 0; j < 4; ++j)
        tile[ty + j * 8][tx] = W[(by * 32 + ty + j * 8) * DIM + bx * 32 + tx];
    __syncthreads();
    #pragma unroll
    for (int j = 0; j < 4; ++j)
        T[(bx * 32 + ty + j * 8) * DIM + by * 32 + tx] = f2bf(tile[tx][ty + j * 8]);
}

// ---------------- GEMM: Cb[M][256](bf16) = A[M][256](bf16) @ W (+bias) ----------------

__global__ __launch_bounds__(256) void gemm_kernel(const unsigned short* __restrict__ A,
                                                   const unsigned short* __restrict__ BT,
                                                   unsigned short* __restrict__ Cb,
                                                   const float* __restrict__ bias) {
    __shared__ __align__(16) unsigned short As[128 * 32];
    __shared__ __align__(16) unsigned short Bs[128 * 32];
    int tid = threadIdx.x;
    int wave = tid >> 6, lane = tid & 63;
    int row0 = blockIdx.x * 128;
    int col0 = blockIdx.y * 128;
    int wm = (wave >> 1) * 64;
    int wn = (wave & 1) * 64;

    f32x4 acc[4][4] = {};

    int fr = lane & 15;
    int kg = (lane >> 4) * 8;

    for (int k0 = 0; k0 < DIM; k0 += 32) {
        #pragma unroll
        for (int r = 0; r < 2; ++r) {
            int row = r * 64 + (tid >> 2);
            int chunk = tid & 3;
            gld_lds16(A + (size_t)(row0 + row) * DIM + k0 + chunk * 8,
                      As + row * 32 + chunk * 8);
            gld_lds16(BT + (size_t)(col0 + row) * DIM + k0 + chunk * 8,
                      Bs + row * 32 + chunk * 8);
        }
        __syncthreads();

        bf16x8 a_frag[4], b_frag[4];
        #pragma unroll
        for (int i = 0; i < 4; ++i) {
            a_frag[i] = *(const bf16x8*)(As + (wm + i * 16 + fr) * 32 + kg);
            b_frag[i] = *(const bf16x8*)(Bs + (wn + i * 16 + fr) * 32 + kg);
        }
        #pragma unroll
        for (int i = 0; i < 4; ++i)
            #pragma unroll
            for (int j = 0; j < 4; ++j)
                acc[i][j] = __builtin_amdgcn_mfma_f32_16x16x32_bf16(
                    a_frag[i], b_frag[j], acc[i][j], 0, 0, 0);
        __syncthreads();
    }

    int rg = (lane >> 4) * 4;
    #pragma unroll
    for (int i = 0; i < 4; ++i) {
        #pragma unroll
        for (int j = 0; j < 4; ++j) {
            int n = col0 + wn + j * 16 + fr;
            float bv = bias ? bias[n] : 0.0f;
            #pragma unroll
            for (int r = 0; r < 4; ++r) {
                int m = row0 + wm + i * 16 + rg + r;
                Cb[(size_t)m * DIM + n] = f2bf(acc[i][j][r] + bv);
            }
        }
    }
}

// ---------------- el/er from bf16 h: one wave per node ----------------

__global__ __launch_bounds__(256) void eler_kernel(const unsigned short* __restrict__ Hb,
                                                   const float* __restrict__ al,
                                                   const float* __restrict__ ar,
                                                   float* __restrict__ el,
                                                   float* __restrict__ er) {
    int wave = threadIdx.x >> 6;
    int lane = threadIdx.x & 63;
    int v = blockIdx.x * 4 + wave;
    if (v >= NNODES) return;
    int c0 = lane * 4;
    ushort4 h = *(const ushort4*)(Hb + (size_t)v * DIM + c0);
    float4 a = *(const float4*)(al + c0);
    float4 r = *(const float4*)(ar + c0);
    float h0 = bf2f(h.x), h1 = bf2f(h.y), h2 = bf2f(h.z), h3 = bf2f(h.w);
    float x = h0 * a.x + h1 * a.y + h2 * a.z + h3 * a.w;
    float y = h0 * r.x + h1 * r.y + h2 * r.z + h3 * r.w;
    #pragma unroll
    for (int off = 1; off < 8; off <<= 1) {
        x += __shfl_xor(x, off, 64);
        y += __shfl_xor(y, off, 64);
    }
    if ((lane & 7) == 0) {
        int head = lane >> 3;
        el[v * NHEAD + head] = x;
        er[v * NHEAD + head] = y;
    }
}

// ---------------- edge softmax + aggregation ----------------
// One wave per dst node; 32 lanes per edge, 2 edges per iteration.
// Lane covers 8 dims (16B bf16x8 gather). Halves reduced via shfl_xor(32).
// Self-loop handled by half 0 only (cross-half sum would double-count).

__global__ __launch_bounds__(256) void agg_kernel(const unsigned short* __restrict__ Hb,
                                                  const float* __restrict__ el,
                                                  const float* __restrict__ er,
                                                  const int* __restrict__ rowptr,
                                                  const int* __restrict__ csr,
                                                  const float* __restrict__ bias,
                                                  float* __restrict__ outf,
                                                  unsigned short* __restrict__ outb) {
    int wave = threadIdx.x >> 6;
    int lane = threadIdx.x & 63;
    int v = blockIdx.x * 4 + wave;
    if (v >= NNODES) return;
    int sub = lane & 31;     // lane within half-wave
    int halfe = lane >> 5;   // which edge of the pair this half handles
    int c0 = sub * 8;        // dim offset (8 dims/lane)
    int head = sub >> 2;     // c0 / 32

    float er_v = er[v * NHEAD + head];
    float el_v = el[v * NHEAD + head];
    int beg = rowptr[v], end = rowptr[v + 1];

    float z = 0.0f;
    float acc[8] = {0.f, 0.f, 0.f, 0.f, 0.f, 0.f, 0.f, 0.f};

    // self loop on half 0 only
    if (halfe == 0) {
        float ws = __expf(leaky(el_v + er_v));
        z = ws;
        bf16x8 h = *(const bf16x8*)(Hb + (size_t)v * DIM + c0);
        #pragma unroll
        for (int d = 0; d < 8; ++d) acc[d] = ws * bf2f_s(h[d]);
    }

    #pragma unroll 4
    for (int i = beg + halfe; i < end; i += 2) {
        int u = csr[i];
        float e = leaky(el[u * NHEAD + head] + er_v);
        float wi = __expf(e);
        z += wi;
        bf16x8 h = *(const bf16x8*)(Hb + (size_t)u * DIM + c0);
        #pragma unroll
        for (int d = 0; d < 8; ++d) acc[d] += wi * bf2f_s(h[d]);
    }

    // cross-half reduction: both halves end with full totals
    z += __shfl_xor(z, 32, 64);
    #pragma unroll
    for (int d = 0; d < 8; ++d) acc[d] += __shfl_xor(acc[d], 32, 64);

    float inv = 1.0f / z;
    // each half stores 4 of the lane's 8 dims: half0 -> dims[0..3], half1 -> dims[4..7]
    int o0 = c0 + halfe * 4;
    float4 b = *(const float4*)(bias + o0);
    float r0 = leaky(acc[halfe * 4 + 0] * inv + b.x);
    float r1 = leaky(acc[halfe * 4 + 1] * inv + b.y);
    float r2 = leaky(acc[halfe * 4 + 2] * inv + b.z);
    float r3 = leaky(acc[halfe * 4 + 3] * inv + b.w);
    if (outf) {
        float4 o = { r0, r1, r2, r3 };
        *(float4*)(outf + (size_t)v * DIM + o0) = o;
    } else {
        u16x4 o;
        o.x = f2bf(r0); o.y = f2bf(r1); o.z = f2bf(r2); o.w = f2bf(r3);
        *(u16x4*)(outb + (size_t)v * DIM + o0) = o;
    }
}

// ---------------- launch ----------------

static inline size_t align256(size_t x) { return (x + 255) & ~(size_t)255; }

extern "C" void kernel_launch(void* const* d_in, const int* in_sizes, int n_in,
                              void* d_out, int out_size, void* d_ws, size_t ws_size,
                              hipStream_t stream) {
    const float* feats  = (const float*)d_in[0];
    const int*   src    = (const int*)d_in[1];
    const int*   dst    = (const int*)d_in[2];
    const float* proj_W = (const float*)d_in[3];
    const float* proj_b = (const float*)d_in[4];
    const float* W1     = (const float*)d_in[5];
    const float* al1    = (const float*)d_in[6];
    const float* ar1    = (const float*)d_in[7];
    const float* b1     = (const float*)d_in[8];
    const float* W2     = (const float*)d_in[9];
    const float* al2    = (const float*)d_in[10];
    const float* ar2    = (const float*)d_in[11];
    const float* b2     = (const float*)d_in[12];
    float* out = (float*)d_out;

    uint8_t* w = (uint8_t*)d_ws;
    unsigned short* Abf = (unsigned short*)w; w += align256((size_t)MPAD * DIM * 2);
    unsigned short* Bbf = (unsigned short*)w; w += align256((size_t)MPAD * DIM * 2);
    unsigned short* Hb  = (unsigned short*)w; w += align256((size_t)MPAD * DIM * 2);
    unsigned short* WT  = (unsigned short*)w; w += align256((size_t)3 * DIM * DIM * 2);
    float* el = (float*)w;            w += align256((size_t)NNODES * NHEAD * 4);
    float* er = (float*)w;            w += align256((size_t)NNODES * NHEAD * 4);
    int* deg    = (int*)w;            w += align256((size_t)NNODES * 4);
    int* rowptr = (int*)w;            w += align256((size_t)(NNODES + 1) * 4);
    int* cursor = (int*)w;            w += align256((size_t)NNODES * 4);
    int* csr    = (int*)w;            w += align256((size_t)NEDGES * 4);
    int* bsum   = (int*)w;            w += align256((size_t)SCAN_BLOCKS * 4);
    int* boff   = (int*)w;            w += align256((size_t)SCAN_BLOCKS * 4);

    unsigned short* WT0 = WT;
    unsigned short* WT1 = WT + (size_t)DIM * DIM;
    unsigned short* WT2 = WT + (size_t)2 * DIM * DIM;

    const int edge_blocks = (NEDGES + 255) / 256;
    const dim3 gemm_grid(MPAD / 128, DIM / 128);
    const int node_wave_blocks = (NNODES + 3) / 4;  // one wave per node

    // CSR build
    hipMemsetAsync(deg, 0, (size_t)NNODES * 4, stream);
    count_kernel<<<edge_blocks, 256, 0, stream>>>(dst, deg);
    scanA_kernel<<<SCAN_BLOCKS, 256, 0, stream>>>(deg, bsum);
    scanB_kernel<<<1, 256, 0, stream>>>(bsum, boff, rowptr);
    scanC_kernel<<<SCAN_BLOCKS, 256, 0, stream>>>(deg, boff, rowptr, cursor);
    fill_kernel<<<edge_blocks, 256, 0, stream>>>(src, dst, cursor, csr);

    // weights (all three) + feats to bf16
    transpose_cvt3<<<dim3(8, 8, 3), 256, 0, stream>>>(proj_W, W1, W2, WT);
    cvt_kernel<<<NNODES * DIM / 1024, 256, 0, stream>>>(feats, Abf);

    // projection: Bbf = bf16(feats @ proj_W + proj_b)
    gemm_kernel<<<gemm_grid, 256, 0, stream>>>(Abf, WT0, Bbf, proj_b);

    // layer 1: Hb = Bbf @ W1 ; agg -> Abf (bf16, input of layer-2 gemm)
    gemm_kernel<<<gemm_grid, 256, 0, stream>>>(Bbf, WT1, Hb, nullptr);
    eler_kernel<<<node_wave_blocks, 256, 0, stream>>>(Hb, al1, ar1, el, er);
    agg_kernel<<<node_wave_blocks, 256, 0, stream>>>(Hb, el, er, rowptr, csr, b1,
                                                     nullptr, Abf);

    // layer 2: Hb = Abf @ W2 ; agg -> out (fp32)
    gemm_kernel<<<gemm_grid, 256, 0, stream>>>(Abf, WT2, Hb, nullptr);
    eler_kernel<<<node_wave_blocks, 256, 0, stream>>>(Hb, al2, ar2, el, er);
    agg_kernel<<<node_wave_blocks, 256, 0, stream>>>(Hb, el, er, rowptr, csr, b2,
                                                     out, nullptr);
}

// Round 5
// 348.716 us; speedup vs baseline: 1.1078x; 1.0244x over previous
//
#include <hip/hip_runtime.h>
#include <stdint.h>
#include <stddef.h>

#define NNODES 50000
#define NEDGES 500000
#define DIM 256
#define NHEAD 8
#define HDIM 32
#define MPAD 50048   /* 391 * 128 */
#define NEGS 0.2f
#define SCAN_BLOCKS 196  /* ceil(50000/256) */

typedef __attribute__((ext_vector_type(8))) short bf16x8;
typedef __attribute__((ext_vector_type(4))) float f32x4;
typedef __attribute__((ext_vector_type(4))) unsigned short u16x4;

__device__ __forceinline__ unsigned short f2bf(float f) {
    uint32_t u = __builtin_bit_cast(uint32_t, f);
    uint32_t r = (u + 0x7FFFu + ((u >> 16) & 1u)) >> 16;
    return (unsigned short)r;
}

__device__ __forceinline__ float bf2f(unsigned short u) {
    return __builtin_bit_cast(float, (uint32_t)u << 16);
}

__device__ __forceinline__ float bf2f_s(short u) {
    return __builtin_bit_cast(float, (uint32_t)(unsigned short)u << 16);
}

__device__ __forceinline__ float leaky(float x) {
    return x > 0.0f ? x : NEGS * x;
}

__device__ __forceinline__ void gld_lds16(const unsigned short* g, unsigned short* l) {
    __builtin_amdgcn_global_load_lds(
        (const __attribute__((address_space(1))) void*)g,
        (__attribute__((address_space(3))) void*)l,
        16, 0, 0);
}

// ---------------- CSR build ----------------

__global__ __launch_bounds__(256) void count_kernel(const int* __restrict__ dst,
                                                    int* __restrict__ deg) {
    int i = blockIdx.x * 256 + threadIdx.x;
    if (i < NEDGES) atomicAdd(&deg[dst[i]], 1);
}

__global__ __launch_bounds__(256) void scanA_kernel(const int* __restrict__ deg,
                                                    int* __restrict__ bsum) {
    __shared__ int ws[4];
    int t = threadIdx.x;
    int idx = blockIdx.x * 256 + t;
    int v = (idx < NNODES) ? deg[idx] : 0;
    int x = v;
    #pragma unroll
    for (int off = 1; off < 64; off <<= 1) x += __shfl_xor(x, off, 64);
    if ((t & 63) == 0) ws[t >> 6] = x;
    __syncthreads();
    if (t == 0) bsum[blockIdx.x] = ws[0] + ws[1] + ws[2] + ws[3];
}

__global__ __launch_bounds__(256) void scanB_kernel(const int* __restrict__ bsum,
                                                    int* __restrict__ boff,
                                                    int* __restrict__ rowptr) {
    __shared__ int s[256];
    int t = threadIdx.x;
    int v = (t < SCAN_BLOCKS) ? bsum[t] : 0;
    s[t] = v;
    __syncthreads();
    #pragma unroll
    for (int off = 1; off < 256; off <<= 1) {
        int y = (t >= off) ? s[t - off] : 0;
        __syncthreads();
        s[t] += y;
        __syncthreads();
    }
    if (t < SCAN_BLOCKS) boff[t] = s[t] - v;  // exclusive
    if (t == 0) rowptr[NNODES] = NEDGES;
}

__global__ __launch_bounds__(256) void scanC_kernel(const int* __restrict__ deg,
                                                    const int* __restrict__ boff,
                                                    int* __restrict__ rowptr,
                                                    int* __restrict__ cursor) {
    __shared__ int ws[4];
    int t = threadIdx.x;
    int lane = t & 63, wv = t >> 6;
    int idx = blockIdx.x * 256 + t;
    int v = (idx < NNODES) ? deg[idx] : 0;
    int x = v;
    #pragma unroll
    for (int off = 1; off < 64; off <<= 1) {
        int y = __shfl_up(x, off, 64);
        if (lane >= off) x += y;
    }
    if (lane == 63) ws[wv] = x;
    __syncthreads();
    int wadd = 0;
    #pragma unroll
    for (int k = 0; k < 4; ++k) if (k < wv) wadd += ws[k];
    int excl = x - v + wadd + boff[blockIdx.x];
    if (idx < NNODES) { rowptr[idx] = excl; cursor[idx] = excl; }
}

__global__ __launch_bounds__(256) void fill_kernel(const int* __restrict__ src,
                                                   const int* __restrict__ dst,
                                                   int* __restrict__ cursor,
                                                   int* __restrict__ csr) {
    int i = blockIdx.x * 256 + threadIdx.x;
    if (i < NEDGES) {
        int pos = atomicAdd(&cursor[dst[i]], 1);
        csr[pos] = src[i];
    }
}

// ---------------- fp32 -> bf16 convert ----------------

__global__ __launch_bounds__(256) void cvt_kernel(const float* __restrict__ x,
                                                  unsigned short* __restrict__ y) {
    int i = (blockIdx.x * 256 + threadIdx.x) * 4;
    const float4 v = *(const float4*)(x + i);
    u16x4 o;
    o.x = f2bf(v.x); o.y = f2bf(v.y); o.z = f2bf(v.z); o.w = f2bf(v.w);
    *(u16x4*)(y + i) = o;
}

// ---------------- W [K][N] fp32 -> WT [N][K] bf16, 3 weights in one dispatch ----------------

__global__ __launch_bounds__(256) void transpose_cvt3(const float* __restrict__ W0,
                                                      const float* __restrict__ W1,
                                                      const float* __restrict__ W2,
                                                      unsigned short* __restrict__ WT) {
    __shared__ float tile[32][33];
    const float* W = (blockIdx.z == 0) ? W0 : (blockIdx.z == 1) ? W1 : W2;
    unsigned short* T = WT + (size_t)blockIdx.z * DIM * DIM;
    int bx = blockIdx.x;  // n tile
    int by = blockIdx.y;  // k tile
    int tx = threadIdx.x & 31, ty = threadIdx.x >> 5;  // 32 x 8
    #pragma unroll
    for (int j = 0; j < 4; ++j)
        tile[ty + j * 8][tx] = W[(by * 32 + ty + j * 8) * DIM + bx * 32 + tx];
    __syncthreads();
    #pragma unroll
    for (int j = 0; j < 4; ++j)
        T[(bx * 32 + ty + j * 8) * DIM + by * 32 + tx] = f2bf(tile[tx][ty + j * 8]);
}

// ---------------- GEMM: Cb[M][256](bf16) = A[M][256](bf16) @ W (+bias) ----------------
// 128x128 tile. K staged in TWO halves of 128 (64 KB LDS total): 16 in-flight
// global_load_lds per thread per stage, 64 MFMA/wave per barrier -> 4 barrier
// drains per block instead of 16 (the m97 barrier-drain tax, quartered).

__global__ __launch_bounds__(256) void gemm_kernel(const unsigned short* __restrict__ A,
                                                   const unsigned short* __restrict__ BT,
                                                   unsigned short* __restrict__ Cb,
                                                   const float* __restrict__ bias) {
    __shared__ __align__(16) unsigned short As[4][128][32];  // 32 KB
    __shared__ __align__(16) unsigned short Bs[4][128][32];  // 32 KB
    int tid = threadIdx.x;
    int wave = tid >> 6, lane = tid & 63;
    int row0 = blockIdx.x * 128;
    int col0 = blockIdx.y * 128;
    int wm = (wave >> 1) * 64;
    int wn = (wave & 1) * 64;

    f32x4 acc[4][4] = {};

    int fr = lane & 15;
    int kg = (lane >> 4) * 8;

    #pragma unroll
    for (int half = 0; half < 2; ++half) {
        int k0 = half * 128;
        // stage A and B for K = [k0, k0+128): each 128 rows x 128 K bf16 (32 KB)
        // linear idx -> LDS offset idx*8 shorts == As[c][row][q*8]
        #pragma unroll
        for (int r = 0; r < 8; ++r) {
            int idx = r * 256 + tid;
            int c = idx >> 9;
            int rem = idx & 511;
            int row = rem >> 2;
            int q = rem & 3;
            gld_lds16(A + (size_t)(row0 + row) * DIM + k0 + c * 32 + q * 8,
                      &As[0][0][0] + idx * 8);
            gld_lds16(BT + (size_t)(col0 + row) * DIM + k0 + c * 32 + q * 8,
                      &Bs[0][0][0] + idx * 8);
        }
        __syncthreads();

        #pragma unroll
        for (int c = 0; c < 4; ++c) {
            bf16x8 a_frag[4], b_frag[4];
            #pragma unroll
            for (int i = 0; i < 4; ++i) {
                a_frag[i] = *(const bf16x8*)(&As[c][wm + i * 16 + fr][kg]);
                b_frag[i] = *(const bf16x8*)(&Bs[c][wn + i * 16 + fr][kg]);
            }
            #pragma unroll
            for (int i = 0; i < 4; ++i)
                #pragma unroll
                for (int j = 0; j < 4; ++j)
                    acc[i][j] = __builtin_amdgcn_mfma_f32_16x16x32_bf16(
                        a_frag[i], b_frag[j], acc[i][j], 0, 0, 0);
        }
        __syncthreads();
    }

    int rg = (lane >> 4) * 4;
    #pragma unroll
    for (int i = 0; i < 4; ++i) {
        #pragma unroll
        for (int j = 0; j < 4; ++j) {
            int n = col0 + wn + j * 16 + fr;
            float bv = bias ? bias[n] : 0.0f;
            #pragma unroll
            for (int r = 0; r < 4; ++r) {
                int m = row0 + wm + i * 16 + rg + r;
                Cb[(size_t)m * DIM + n] = f2bf(acc[i][j][r] + bv);
            }
        }
    }
}

// ---------------- el/er from bf16 h: one wave per node ----------------

__global__ __launch_bounds__(256) void eler_kernel(const unsigned short* __restrict__ Hb,
                                                   const float* __restrict__ al,
                                                   const float* __restrict__ ar,
                                                   float* __restrict__ el,
                                                   float* __restrict__ er) {
    int wave = threadIdx.x >> 6;
    int lane = threadIdx.x & 63;
    int v = blockIdx.x * 4 + wave;
    if (v >= NNODES) return;
    int c0 = lane * 4;
    ushort4 h = *(const ushort4*)(Hb + (size_t)v * DIM + c0);
    float4 a = *(const float4*)(al + c0);
    float4 r = *(const float4*)(ar + c0);
    float h0 = bf2f(h.x), h1 = bf2f(h.y), h2 = bf2f(h.z), h3 = bf2f(h.w);
    float x = h0 * a.x + h1 * a.y + h2 * a.z + h3 * a.w;
    float y = h0 * r.x + h1 * r.y + h2 * r.z + h3 * r.w;
    #pragma unroll
    for (int off = 1; off < 8; off <<= 1) {
        x += __shfl_xor(x, off, 64);
        y += __shfl_xor(y, off, 64);
    }
    if ((lane & 7) == 0) {
        int head = lane >> 3;
        el[v * NHEAD + head] = x;
        er[v * NHEAD + head] = y;
    }
}

// ---------------- edge softmax + aggregation ----------------
// One wave per dst node; 32 lanes per edge, 2 edges per iteration.
// Lane covers 8 dims (16B bf16x8 gather). Halves reduced via shfl_xor(32).
// Self-loop handled by half 0 only (cross-half sum would double-count).

__global__ __launch_bounds__(256) void agg_kernel(const unsigned short* __restrict__ Hb,
                                                  const float* __restrict__ el,
                                                  const float* __restrict__ er,
                                                  const int* __restrict__ rowptr,
                                                  const int* __restrict__ csr,
                                                  const float* __restrict__ bias,
                                                  float* __restrict__ outf,
                                                  unsigned short* __restrict__ outb) {
    int wave = threadIdx.x >> 6;
    int lane = threadIdx.x & 63;
    int v = blockIdx.x * 4 + wave;
    if (v >= NNODES) return;
    int sub = lane & 31;     // lane within half-wave
    int halfe = lane >> 5;   // which edge of the pair this half handles
    int c0 = sub * 8;        // dim offset (8 dims/lane)
    int head = sub >> 2;     // c0 / 32

    float er_v = er[v * NHEAD + head];
    float el_v = el[v * NHEAD + head];
    int beg = rowptr[v], end = rowptr[v + 1];

    float z = 0.0f;
    float acc[8] = {0.f, 0.f, 0.f, 0.f, 0.f, 0.f, 0.f, 0.f};

    // self loop on half 0 only
    if (halfe == 0) {
        float ws = __expf(leaky(el_v + er_v));
        z = ws;
        bf16x8 h = *(const bf16x8*)(Hb + (size_t)v * DIM + c0);
        #pragma unroll
        for (int d = 0; d < 8; ++d) acc[d] = ws * bf2f_s(h[d]);
    }

    #pragma unroll 4
    for (int i = beg + halfe; i < end; i += 2) {
        int u = csr[i];
        float e = leaky(el[u * NHEAD + head] + er_v);
        float wi = __expf(e);
        z += wi;
        bf16x8 h = *(const bf16x8*)(Hb + (size_t)u * DIM + c0);
        #pragma unroll
        for (int d = 0; d < 8; ++d) acc[d] += wi * bf2f_s(h[d]);
    }

    // cross-half reduction: both halves end with full totals
    z += __shfl_xor(z, 32, 64);
    #pragma unroll
    for (int d = 0; d < 8; ++d) acc[d] += __shfl_xor(acc[d], 32, 64);

    float inv = 1.0f / z;
    // each half stores 4 of the lane's 8 dims: half0 -> dims[0..3], half1 -> dims[4..7]
    int o0 = c0 + halfe * 4;
    float4 b = *(const float4*)(bias + o0);
    float r0 = leaky(acc[halfe * 4 + 0] * inv + b.x);
    float r1 = leaky(acc[halfe * 4 + 1] * inv + b.y);
    float r2 = leaky(acc[halfe * 4 + 2] * inv + b.z);
    float r3 = leaky(acc[halfe * 4 + 3] * inv + b.w);
    if (outf) {
        float4 o = { r0, r1, r2, r3 };
        *(float4*)(outf + (size_t)v * DIM + o0) = o;
    } else {
        u16x4 o;
        o.x = f2bf(r0); o.y = f2bf(r1); o.z = f2bf(r2); o.w = f2bf(r3);
        *(u16x4*)(outb + (size_t)v * DIM + o0) = o;
    }
}

// ---------------- launch ----------------

static inline size_t align256(size_t x) { return (x + 255) & ~(size_t)255; }

extern "C" void kernel_launch(void* const* d_in, const int* in_sizes, int n_in,
                              void* d_out, int out_size, void* d_ws, size_t ws_size,
                              hipStream_t stream) {
    const float* feats  = (const float*)d_in[0];
    const int*   src    = (const int*)d_in[1];
    const int*   dst    = (const int*)d_in[2];
    const float* proj_W = (const float*)d_in[3];
    const float* proj_b = (const float*)d_in[4];
    const float* W1     = (const float*)d_in[5];
    const float* al1    = (const float*)d_in[6];
    const float* ar1    = (const float*)d_in[7];
    const float* b1     = (const float*)d_in[8];
    const float* W2     = (const float*)d_in[9];
    const float* al2    = (const float*)d_in[10];
    const float* ar2    = (const float*)d_in[11];
    const float* b2     = (const float*)d_in[12];
    float* out = (float*)d_out;

    uint8_t* w = (uint8_t*)d_ws;
    unsigned short* Abf = (unsigned short*)w; w += align256((size_t)MPAD * DIM * 2);
    unsigned short* Bbf = (unsigned short*)w; w += align256((size_t)MPAD * DIM * 2);
    unsigned short* Hb  = (unsigned short*)w; w += align256((size_t)MPAD * DIM * 2);
    unsigned short* WT  = (unsigned short*)w; w += align256((size_t)3 * DIM * DIM * 2);
    float* el = (float*)w;            w += align256((size_t)NNODES * NHEAD * 4);
    float* er = (float*)w;            w += align256((size_t)NNODES * NHEAD * 4);
    int* deg    = (int*)w;            w += align256((size_t)NNODES * 4);
    int* rowptr = (int*)w;            w += align256((size_t)(NNODES + 1) * 4);
    int* cursor = (int*)w;            w += align256((size_t)NNODES * 4);
    int* csr    = (int*)w;            w += align256((size_t)NEDGES * 4);
    int* bsum   = (int*)w;            w += align256((size_t)SCAN_BLOCKS * 4);
    int* boff   = (int*)w;            w += align256((size_t)SCAN_BLOCKS * 4);

    unsigned short* WT0 = WT;
    unsigned short* WT1 = WT + (size_t)DIM * DIM;
    unsigned short* WT2 = WT + (size_t)2 * DIM * DIM;

    const int edge_blocks = (NEDGES + 255) / 256;
    const dim3 gemm_grid(MPAD / 128, DIM / 128);
    const int node_wave_blocks = (NNODES + 3) / 4;  // one wave per node

    // CSR build
    hipMemsetAsync(deg, 0, (size_t)NNODES * 4, stream);
    count_kernel<<<edge_blocks, 256, 0, stream>>>(dst, deg);
    scanA_kernel<<<SCAN_BLOCKS, 256, 0, stream>>>(deg, bsum);
    scanB_kernel<<<1, 256, 0, stream>>>(bsum, boff, rowptr);
    scanC_kernel<<<SCAN_BLOCKS, 256, 0, stream>>>(deg, boff, rowptr, cursor);
    fill_kernel<<<edge_blocks, 256, 0, stream>>>(src, dst, cursor, csr);

    // weights (all three) + feats to bf16
    transpose_cvt3<<<dim3(8, 8, 3), 256, 0, stream>>>(proj_W, W1, W2, WT);
    cvt_kernel<<<NNODES * DIM / 1024, 256, 0, stream>>>(feats, Abf);

    // projection: Bbf = bf16(feats @ proj_W + proj_b)
    gemm_kernel<<<gemm_grid, 256, 0, stream>>>(Abf, WT0, Bbf, proj_b);

    // layer 1: Hb = Bbf @ W1 ; agg -> Abf (bf16, input of layer-2 gemm)
    gemm_kernel<<<gemm_grid, 256, 0, stream>>>(Bbf, WT1, Hb, nullptr);
    eler_kernel<<<node_wave_blocks, 256, 0, stream>>>(Hb, al1, ar1, el, er);
    agg_kernel<<<node_wave_blocks, 256, 0, stream>>>(Hb, el, er, rowptr, csr, b1,
                                                     nullptr, Abf);

    // layer 2: Hb = Abf @ W2 ; agg -> out (fp32)
    gemm_kernel<<<gemm_grid, 256, 0, stream>>>(Abf, WT2, Hb, nullptr);
    eler_kernel<<<node_wave_blocks, 256, 0, stream>>>(Hb, al2, ar2, el, er);
    agg_kernel<<<node_wave_blocks, 256, 0, stream>>>(Hb, el, er, rowptr, csr, b2,
                                                     out, nullptr);
}